// Round 1
// 151.615 us; speedup vs baseline: 1.0637x; 1.0637x over previous
//
#include <hip/hip_runtime.h>
#include <math.h>

#define N_PTS     131072
#define G_NUMS    30
#define G_SIZE    100
#define PT_STRIDE (N_PTS / G_NUMS)   // 4369
#define TPB       512
#define NWAVES    (TPB / 64)
#define BINS      4096
#define SHIFT     20
#define SAMPLE_GRPS 1024             // first 4096 points as iid sample
#define RANK_CUT  32                 // 32nd-smallest sample -> tau (P(fail) ~ 1e-25)
#define CAP       3072               // survivor capacity (~11 sigma above mean ~1024)
#define TIE_CAP   64

struct KSmem {
    unsigned hist[BINS];
    unsigned wsum[NWAVES];
    unsigned T;
    int ns, nd, nt;
    unsigned u[CAP];
    int idx[CAP];
    int sel[G_SIZE];
    unsigned tu[TIE_CAP];
    int ti[TIE_CAP];
    float acc[3];
    float cov[6];
    float q[3];
    unsigned tau0;     // phase-0 coarse threshold (float bits)
    unsigned maxu;     // max survivor distance to q1 (bits)
    unsigned r1;       // 100th-NN distance to q1 among survivors (bits)
    float delta2;      // ||q1 - q0||^2
    int fastok;
};

__device__ __forceinline__ float dist2f(float px, float py, float pz,
                                        float qx, float qy, float qz) {
    float dx = px - qx, dy = py - qy, dz = pz - qz;
    return fmaf(dx, dx, fmaf(dy, dy, dz * dz));
}

// Find smallest bin T such that cumulative count through T >= rank.
__device__ __forceinline__ unsigned find_bin(KSmem& sm, unsigned rank,
                                             int tid, int lane, int wid) {
    unsigned hv[8], csum = 0;
#pragma unroll
    for (int j = 0; j < 8; j++) { hv[j] = sm.hist[tid * 8 + j]; csum += hv[j]; }
    unsigned inc = csum;
#pragma unroll
    for (int off = 1; off < 64; off <<= 1) {
        unsigned n = __shfl_up(inc, off);
        if (lane >= off) inc += n;
    }
    __syncthreads();                  // protect wsum reuse across calls
    if (lane == 63) sm.wsum[wid] = inc;
    __syncthreads();
    unsigned base = 0;
    for (int w = 0; w < wid; w++) base += sm.wsum[w];
    unsigned c = base + inc - csum;   // exclusive prefix before this thread's chunk
#pragma unroll
    for (int j = 0; j < 8; j++) {
        if (c < rank && c + hv[j] >= rank) sm.T = (unsigned)(tid * 8 + j);
        c += hv[j];
    }
    __syncthreads();
    return sm.T;
}

template<bool SOA>
__device__ __forceinline__ void load_pt(const float* __restrict__ P,
                                        const float* __restrict__ BX,
                                        const float* __restrict__ BY,
                                        const float* __restrict__ BZ,
                                        int idx, float& x, float& y, float& z) {
    if constexpr (SOA) {
        x = BX[idx]; y = BY[idx]; z = BZ[idx];
    } else {
        const float* pp = P + 3 * (size_t)idx;
        x = pp[0]; y = pp[1]; z = pp[2];
    }
}

// Exact 100-NN of (qx,qy,qz): sample tau -> filter scan -> fine histogram select.
// Leaves: sm.sel[0..99] selected indices, sm.ns raw survivor count,
//         sm.u/idx survivor (dist-bits, index) pairs, sm.tau0 if save_tau.
template<bool SOA>
__device__ void full_select(const float4* __restrict__ P4,
                            const float4* __restrict__ X4,
                            const float4* __restrict__ Y4,
                            const float4* __restrict__ Z4,
                            KSmem& sm, float qx, float qy, float qz,
                            int tid, int lane, int wid, bool save_tau) {
    for (int j = tid; j < BINS; j += TPB) sm.hist[j] = 0u;
    if (tid == 0) { sm.ns = 0; sm.nd = 0; sm.nt = 0; sm.T = 0u; }
    __syncthreads();

    // ---- sample scan: 4096 distances -> coarse histogram ----
    if constexpr (SOA) {
        for (int i = tid; i < SAMPLE_GRPS; i += TPB) {
            float4 xv = X4[i], yv = Y4[i], zv = Z4[i];
            atomicAdd(&sm.hist[__float_as_uint(dist2f(xv.x, yv.x, zv.x, qx, qy, qz)) >> SHIFT], 1u);
            atomicAdd(&sm.hist[__float_as_uint(dist2f(xv.y, yv.y, zv.y, qx, qy, qz)) >> SHIFT], 1u);
            atomicAdd(&sm.hist[__float_as_uint(dist2f(xv.z, yv.z, zv.z, qx, qy, qz)) >> SHIFT], 1u);
            atomicAdd(&sm.hist[__float_as_uint(dist2f(xv.w, yv.w, zv.w, qx, qy, qz)) >> SHIFT], 1u);
        }
    } else {
        for (int grp = tid; grp < SAMPLE_GRPS; grp += TPB) {
            float4 f0 = P4[3 * grp + 0];
            float4 f1 = P4[3 * grp + 1];
            float4 f2 = P4[3 * grp + 2];
            atomicAdd(&sm.hist[__float_as_uint(dist2f(f0.x, f0.y, f0.z, qx, qy, qz)) >> SHIFT], 1u);
            atomicAdd(&sm.hist[__float_as_uint(dist2f(f0.w, f1.x, f1.y, qx, qy, qz)) >> SHIFT], 1u);
            atomicAdd(&sm.hist[__float_as_uint(dist2f(f1.z, f1.w, f2.x, qx, qy, qz)) >> SHIFT], 1u);
            atomicAdd(&sm.hist[__float_as_uint(dist2f(f2.y, f2.z, f2.w, qx, qy, qz)) >> SHIFT], 1u);
        }
    }
    __syncthreads();
    unsigned Tc = find_bin(sm, RANK_CUT, tid, lane, wid);
    const unsigned tau = (Tc >= BINS - 1) ? 0xFFFFFFFFu : ((Tc + 1) << SHIFT);
    if (save_tau && tid == 0) sm.tau0 = tau;
    // re-zero hist for the fine pass
    for (int j = tid; j < BINS; j += TPB) sm.hist[j] = 0u;
    __syncthreads();

    // ---- full scan: pure filter, rare compaction (hit rate ~1/128) ----
    if constexpr (SOA) {
#pragma unroll 4
        for (int i = tid; i < N_PTS / 4; i += TPB) {
            float4 xv = X4[i], yv = Y4[i], zv = Z4[i];
            unsigned u0 = __float_as_uint(dist2f(xv.x, yv.x, zv.x, qx, qy, qz));
            unsigned u1 = __float_as_uint(dist2f(xv.y, yv.y, zv.y, qx, qy, qz));
            unsigned u2 = __float_as_uint(dist2f(xv.z, yv.z, zv.z, qx, qy, qz));
            unsigned u3 = __float_as_uint(dist2f(xv.w, yv.w, zv.w, qx, qy, qz));
            int i0 = i * 4;
            if (u0 < tau) { int p = atomicAdd(&sm.ns, 1); if (p < CAP) { sm.u[p] = u0; sm.idx[p] = i0; } }
            if (u1 < tau) { int p = atomicAdd(&sm.ns, 1); if (p < CAP) { sm.u[p] = u1; sm.idx[p] = i0 + 1; } }
            if (u2 < tau) { int p = atomicAdd(&sm.ns, 1); if (p < CAP) { sm.u[p] = u2; sm.idx[p] = i0 + 2; } }
            if (u3 < tau) { int p = atomicAdd(&sm.ns, 1); if (p < CAP) { sm.u[p] = u3; sm.idx[p] = i0 + 3; } }
        }
    } else {
#pragma unroll 4
        for (int grp = tid; grp < N_PTS / 4; grp += TPB) {
            float4 f0 = P4[3 * grp + 0];
            float4 f1 = P4[3 * grp + 1];
            float4 f2 = P4[3 * grp + 2];
            unsigned u0 = __float_as_uint(dist2f(f0.x, f0.y, f0.z, qx, qy, qz));
            unsigned u1 = __float_as_uint(dist2f(f0.w, f1.x, f1.y, qx, qy, qz));
            unsigned u2 = __float_as_uint(dist2f(f1.z, f1.w, f2.x, qx, qy, qz));
            unsigned u3 = __float_as_uint(dist2f(f2.y, f2.z, f2.w, qx, qy, qz));
            int i0 = grp * 4;
            if (u0 < tau) { int p = atomicAdd(&sm.ns, 1); if (p < CAP) { sm.u[p] = u0; sm.idx[p] = i0; } }
            if (u1 < tau) { int p = atomicAdd(&sm.ns, 1); if (p < CAP) { sm.u[p] = u1; sm.idx[p] = i0 + 1; } }
            if (u2 < tau) { int p = atomicAdd(&sm.ns, 1); if (p < CAP) { sm.u[p] = u2; sm.idx[p] = i0 + 2; } }
            if (u3 < tau) { int p = atomicAdd(&sm.ns, 1); if (p < CAP) { sm.u[p] = u3; sm.idx[p] = i0 + 3; } }
        }
    }
    __syncthreads();
    int S = sm.ns; if (S > CAP) S = CAP;

    // ---- fine histogram over survivors: exact rank-100 bin ----
    unsigned hb = 32u - (unsigned)__clz(tau - 1u);
    unsigned s2 = hb > 12u ? hb - 12u : 0u;
    for (int i = tid; i < S; i += TPB) atomicAdd(&sm.hist[sm.u[i] >> s2], 1u);
    __syncthreads();
    unsigned T2 = find_bin(sm, G_SIZE, tid, lane, wid);
    const unsigned lo = T2 << s2;

    // ---- collect definite + ties ----
    for (int i = tid; i < S; i += TPB) {
        unsigned uu = sm.u[i];
        if (uu < lo) {
            int p = atomicAdd(&sm.nd, 1);
            if (p < G_SIZE) sm.sel[p] = sm.idx[i];
        } else if ((uu >> s2) == T2) {
            int p = atomicAdd(&sm.nt, 1);
            if (p < TIE_CAP) { sm.tu[p] = uu; sm.ti[p] = sm.idx[i]; }
        }
    }
    __syncthreads();
    if (tid == 0) {
        int nd = sm.nd; if (nd > G_SIZE) nd = G_SIZE;
        int need = G_SIZE - nd;
        int ec = sm.nt; if (ec > TIE_CAP) ec = TIE_CAP;
        for (int a = 0; a < need && a < ec; ++a) {
            int best = a;
            for (int j = a + 1; j < ec; ++j)
                if (sm.tu[j] < sm.tu[best] ||
                    (sm.tu[j] == sm.tu[best] && sm.ti[j] < sm.ti[best])) best = j;
            unsigned tub = sm.tu[best]; sm.tu[best] = sm.tu[a]; sm.tu[a] = tub;
            int tib = sm.ti[best]; sm.ti[best] = sm.ti[a]; sm.ti[a] = tib;
            sm.sel[nd + a] = sm.ti[a];
        }
    }
    __syncthreads();
}

// One block per (batch, group).
// Phase 0: exact 100-NN of strided center -> mean (q1).
// Phase 1: exact 100-NN of q1 via certified survivor reuse; full-scan fallback.
template<bool SOA>
__global__ __launch_bounds__(TPB)
void fused_knn_kernel(const float* __restrict__ pts,
                      const float* __restrict__ sx, const float* __restrict__ sy,
                      const float* __restrict__ sz,
                      float* __restrict__ out_mean, float* __restrict__ out_cov,
                      int B) {
    __shared__ KSmem sm;

    const int blk = blockIdx.x;
    const int b = blk % B;           // batch-per-XCD swizzle (L2 locality)
    const int g = blk / B;
    const int gi = b * G_NUMS + g;   // b-major for finalize
    const float* __restrict__ P = pts + (size_t)b * (N_PTS * 3);
    const float4* __restrict__ P4 = (const float4*)P;
    const float* BX = nullptr; const float* BY = nullptr; const float* BZ = nullptr;
    const float4* X4 = nullptr; const float4* Y4 = nullptr; const float4* Z4 = nullptr;
    if constexpr (SOA) {
        BX = sx + (size_t)b * N_PTS;
        BY = sy + (size_t)b * N_PTS;
        BZ = sz + (size_t)b * N_PTS;
        X4 = (const float4*)BX; Y4 = (const float4*)BY; Z4 = (const float4*)BZ;
    }
    const int tid = threadIdx.x;
    const int lane = tid & 63, wid = tid >> 6;

    if (tid == 0) {
        const float* qp = P + (size_t)g * PT_STRIDE * 3;
        sm.q[0] = qp[0]; sm.q[1] = qp[1]; sm.q[2] = qp[2];
    }
    if (tid < 3) sm.acc[tid] = 0.f;
    if (tid < 6) sm.cov[tid] = 0.f;
    __syncthreads();
    const float qx = sm.q[0], qy = sm.q[1], qz = sm.q[2];

    // ================= phase 0 =================
    full_select<SOA>(P4, X4, Y4, Z4, sm, qx, qy, qz, tid, lane, wid, true);

    if (tid < G_SIZE) {
        float x, y, z;
        load_pt<SOA>(P, BX, BY, BZ, sm.sel[tid], x, y, z);
        atomicAdd(&sm.acc[0], x);
        atomicAdd(&sm.acc[1], y);
        atomicAdd(&sm.acc[2], z);
    }
    __syncthreads();
    const int S0 = sm.ns;            // raw phase-0 survivor count
    if (tid == 0) {
        float mx = sm.acc[0] * (1.0f / G_SIZE);
        float my = sm.acc[1] * (1.0f / G_SIZE);
        float mz = sm.acc[2] * (1.0f / G_SIZE);
        out_mean[(size_t)gi * 3 + 0] = mx;
        out_mean[(size_t)gi * 3 + 1] = my;
        out_mean[(size_t)gi * 3 + 2] = mz;
        float dx = mx - qx, dy = my - qy, dz = mz - qz;
        sm.delta2 = fmaf(dx, dx, fmaf(dy, dy, dz * dz));
        sm.q[0] = mx; sm.q[1] = my; sm.q[2] = mz;
        sm.acc[0] = 0.f; sm.acc[1] = 0.f; sm.acc[2] = 0.f;
        sm.maxu = 0u; sm.r1 = 0u; sm.T = 0u;
        sm.nd = 0; sm.nt = 0;
        sm.fastok = 0;
    }
    __syncthreads();
    const float q1x = sm.q[0], q1y = sm.q[1], q1z = sm.q[2];

    // ============ phase 1 fast path: certified survivor reuse ============
    const bool attempt = (S0 >= G_SIZE) && (S0 <= CAP);  // complete survivor set
    if (attempt) {
        for (int j = tid; j < BINS; j += TPB) sm.hist[j] = 0u;
        for (int i = tid; i < S0; i += TPB) {
            float x, y, z;
            load_pt<SOA>(P, BX, BY, BZ, sm.idx[i], x, y, z);
            unsigned uu = __float_as_uint(dist2f(x, y, z, q1x, q1y, q1z));
            sm.u[i] = uu;
            atomicMax(&sm.maxu, uu);
        }
        __syncthreads();
        unsigned maxu = sm.maxu;
        unsigned hb = (maxu == 0u) ? 0u : (32u - (unsigned)__clz(maxu));
        unsigned s3 = hb > 12u ? hb - 12u : 0u;
        for (int i = tid; i < S0; i += TPB) atomicAdd(&sm.hist[sm.u[i] >> s3], 1u);
        __syncthreads();
        unsigned T2 = find_bin(sm, G_SIZE, tid, lane, wid);
        const unsigned lo = T2 << s3;
        for (int i = tid; i < S0; i += TPB) {
            unsigned uu = sm.u[i];
            if (uu < lo) {
                int p = atomicAdd(&sm.nd, 1);
                if (p < G_SIZE) sm.sel[p] = sm.idx[i];
            } else if ((uu >> s3) == T2) {
                int p = atomicAdd(&sm.nt, 1);
                if (p < TIE_CAP) { sm.tu[p] = uu; sm.ti[p] = sm.idx[i]; }
            }
        }
        __syncthreads();
        if (tid == 0) {
            int ok = 1;
            int nd = sm.nd; if (nd > G_SIZE) { nd = G_SIZE; ok = 0; }
            int need = G_SIZE - nd;
            if (sm.nt > TIE_CAP) ok = 0;
            int ec = sm.nt; if (ec > TIE_CAP) ec = TIE_CAP;
            if (need > ec) ok = 0;
            for (int a = 0; a < need && a < ec; ++a) {
                int best = a;
                for (int j = a + 1; j < ec; ++j)
                    if (sm.tu[j] < sm.tu[best] ||
                        (sm.tu[j] == sm.tu[best] && sm.ti[j] < sm.ti[best])) best = j;
                unsigned tub = sm.tu[best]; sm.tu[best] = sm.tu[a]; sm.tu[a] = tub;
                int tib = sm.ti[best]; sm.ti[best] = sm.ti[a]; sm.ti[a] = tib;
                sm.sel[nd + a] = sm.ti[a];
            }
            sm.fastok = ok;
        }
        __syncthreads();
        if (sm.fastok) {
            if (tid < G_SIZE) {
                float x, y, z;
                load_pt<SOA>(P, BX, BY, BZ, sm.sel[tid], x, y, z);
                atomicMax(&sm.r1, __float_as_uint(dist2f(x, y, z, q1x, q1y, q1z)));
            }
            __syncthreads();
            if (tid == 0) {
                // certificate: every non-survivor p has d0(p) >= R0, so
                // d1(p) >= R0 - delta; exact iff R0 - delta > r1 (with fp margin)
                double R0 = sqrt((double)__uint_as_float(sm.tau0));
                double dl = sqrt((double)sm.delta2);
                double r1 = sqrt((double)__uint_as_float(sm.r1));
                if (!((R0 - dl) > r1 * 1.0001 + 1e-7)) sm.fastok = 0;
            }
            __syncthreads();
        }
    }

    // ============ phase 1 fallback: exact full scan (rare) ============
    if (!attempt || !sm.fastok) {
        full_select<SOA>(P4, X4, Y4, Z4, sm, q1x, q1y, q1z, tid, lane, wid, false);
    }

    // ============ common tail: mean / covariance over the exact 100 ============
    float px = 0.f, py = 0.f, pz = 0.f;
    if (tid < G_SIZE) {
        load_pt<SOA>(P, BX, BY, BZ, sm.sel[tid], px, py, pz);
        atomicAdd(&sm.acc[0], px);
        atomicAdd(&sm.acc[1], py);
        atomicAdd(&sm.acc[2], pz);
    }
    __syncthreads();
    float mx = sm.acc[0] * (1.0f / G_SIZE);
    float my = sm.acc[1] * (1.0f / G_SIZE);
    float mz = sm.acc[2] * (1.0f / G_SIZE);
    if (tid < G_SIZE) {
        float x = px - mx, y = py - my, z = pz - mz;
        atomicAdd(&sm.cov[0], x * x);
        atomicAdd(&sm.cov[1], x * y);
        atomicAdd(&sm.cov[2], x * z);
        atomicAdd(&sm.cov[3], y * y);
        atomicAdd(&sm.cov[4], y * z);
        atomicAdd(&sm.cov[5], z * z);
    }
    __syncthreads();
    if (tid < 6) out_cov[(size_t)gi * 6 + tid] = sm.cov[tid] * (1.0f / G_SIZE);
}

// AoS -> SoA transpose: point k of batch b lands at [b*N + k] in each of sx/sy/sz.
__global__ __launch_bounds__(256)
void transpose_kernel(const float* __restrict__ pts,
                      float* __restrict__ sx, float* __restrict__ sy,
                      float* __restrict__ sz, int total4) {
    int t = blockIdx.x * 256 + threadIdx.x;
    if (t >= total4) return;
    const float4* __restrict__ P4 = (const float4*)pts;
    float4 f0 = P4[3 * t + 0];
    float4 f1 = P4[3 * t + 1];
    float4 f2 = P4[3 * t + 2];
    ((float4*)sx)[t] = make_float4(f0.x, f0.w, f1.z, f2.y);
    ((float4*)sy)[t] = make_float4(f0.y, f1.x, f1.w, f2.z);
    ((float4*)sz)[t] = make_float4(f0.z, f1.y, f2.x, f2.w);
}

// ---- 3x3 symmetric eigensolve (Jacobi, double) ----
__device__ void eig3(const float cf[6], double lam_out[3], double dir_out[3]) {
    double a[3][3], v[3][3];
    a[0][0] = cf[0]; a[0][1] = cf[1]; a[0][2] = cf[2];
    a[1][0] = cf[1]; a[1][1] = cf[3]; a[1][2] = cf[4];
    a[2][0] = cf[2]; a[2][1] = cf[4]; a[2][2] = cf[5];
    for (int i = 0; i < 3; i++)
        for (int j = 0; j < 3; j++) v[i][j] = (i == j) ? 1.0 : 0.0;

    for (int sweep = 0; sweep < 12; sweep++) {
        double off = a[0][1] * a[0][1] + a[0][2] * a[0][2] + a[1][2] * a[1][2];
        if (off == 0.0) break;
        for (int p = 0; p < 2; p++) {
            for (int q = p + 1; q < 3; q++) {
                double apq = a[p][q];
                if (apq == 0.0) continue;
                double app = a[p][p], aqq = a[q][q];
                double theta = (aqq - app) / (2.0 * apq);
                double t = (theta >= 0.0 ? 1.0 : -1.0) /
                           (fabs(theta) + sqrt(theta * theta + 1.0));
                double c = 1.0 / sqrt(t * t + 1.0);
                double s = t * c;
                a[p][p] = app - t * apq;
                a[q][q] = aqq + t * apq;
                a[p][q] = 0.0; a[q][p] = 0.0;
                for (int r = 0; r < 3; r++) {
                    if (r == p || r == q) continue;
                    double arp = a[r][p], arq = a[r][q];
                    a[r][p] = c * arp - s * arq; a[p][r] = a[r][p];
                    a[r][q] = s * arp + c * arq; a[q][r] = a[r][q];
                }
                for (int r = 0; r < 3; r++) {
                    double vrp = v[r][p], vrq = v[r][q];
                    v[r][p] = c * vrp - s * vrq;
                    v[r][q] = s * vrp + c * vrq;
                }
            }
        }
    }
    double l0 = a[0][0], l1 = a[1][1], l2 = a[2][2];
    int i0 = 0, i1 = 1, i2 = 2;
    if (l0 > l1) { double t = l0; l0 = l1; l1 = t; int ti = i0; i0 = i1; i1 = ti; }
    if (l1 > l2) { double t = l1; l1 = l2; l2 = t; int ti = i1; i1 = i2; i2 = ti; }
    if (l0 > l1) { double t = l0; l0 = l1; l1 = t; int ti = i0; i0 = i1; i1 = ti; }
    lam_out[0] = l0; lam_out[1] = l1; lam_out[2] = l2;
    dir_out[0] = v[0][i2]; dir_out[1] = v[1][i2]; dir_out[2] = v[2][i2];
}

__global__ __launch_bounds__(256)
void finalize_kernel(const float* __restrict__ gmeans, const float* __restrict__ covs,
                     float* __restrict__ out, int B) {
    const int tid = threadIdx.x;
    const int NG = B * G_NUMS;   // 240
    __shared__ float s_dir[256][3];
    __shared__ float s_gm[256][3];
    __shared__ float s_pe[4];
    __shared__ float s_ps[4];

    float et = 0.f;
    if (tid < NG) {
        float cf[6];
#pragma unroll
        for (int j = 0; j < 6; j++) cf[j] = covs[tid * 6 + j];
        double lam[3], dir[3];
        eig3(cf, lam, dir);
        double denom = lam[0] + lam[1] + lam[2] + 1e-9;
        et = (float)((lam[2] - lam[1]) / denom);
        s_dir[tid][0] = (float)dir[0];
        s_dir[tid][1] = (float)dir[1];
        s_dir[tid][2] = (float)dir[2];
        s_gm[tid][0] = gmeans[tid * 3 + 0];
        s_gm[tid][1] = gmeans[tid * 3 + 1];
        s_gm[tid][2] = gmeans[tid * 3 + 2];
    }
    __syncthreads();

    float st = 0.f;
    if (tid < NG) {
        int b = tid / G_NUMS, g = tid % G_NUMS;
        float gx = s_gm[tid][0], gy = s_gm[tid][1], gz = s_gm[tid][2];
        float bd = 3.4e38f; int bj = 0;
        for (int gg = 0; gg < G_NUMS; gg++) {
            if (gg == g) continue;
            int o = b * G_NUMS + gg;
            float dx = gx - s_gm[o][0];
            float dy = gy - s_gm[o][1];
            float dz = gz - s_gm[o][2];
            float d = dx * dx + dy * dy + dz * dz;
            if (d < bd) { bd = d; bj = gg; }
        }
        int o = b * G_NUMS + bj;
        float cosv = s_dir[tid][0] * s_dir[o][0] +
                     s_dir[tid][1] * s_dir[o][1] +
                     s_dir[tid][2] * s_dir[o][2];
        st = 1.f - cosv * cosv;
    }

    float e = et, s2 = st;
#pragma unroll
    for (int off = 32; off > 0; off >>= 1) {
        e += __shfl_down(e, off);
        s2 += __shfl_down(s2, off);
    }
    int lane = tid & 63, wid = tid >> 6;
    if (lane == 0) { s_pe[wid] = e; s_ps[wid] = s2; }
    __syncthreads();
    if (tid == 0) {
        float se = 0.f, ss = 0.f;
        for (int w = 0; w < 4; w++) { se += s_pe[w]; ss += s_ps[w]; }
        out[0] = -se / (float)B + ss / (float)NG;
    }
}

extern "C" void kernel_launch(void* const* d_in, const int* in_sizes, int n_in,
                              void* d_out, int out_size, void* d_ws, size_t ws_size,
                              hipStream_t stream) {
    const float* pts = (const float*)d_in[0];
    float* out = (float*)d_out;
    float* ws = (float*)d_ws;
    int B = in_sizes[0] / (N_PTS * 3);   // 8
    float* gmeans = ws;                          // B*G_NUMS*3 floats
    float* covs = ws + (size_t)B * G_NUMS * 3;   // B*G_NUMS*6 floats

    const size_t base_floats = (size_t)B * G_NUMS * 9;
    const size_t soa_floats = 3 * (size_t)B * N_PTS;
    const bool use_soa = ws_size >= (base_floats + soa_floats) * sizeof(float);

    dim3 grid(B * G_NUMS);
    if (use_soa) {
        float* sx = ws + base_floats;
        float* sy = sx + (size_t)B * N_PTS;
        float* sz = sy + (size_t)B * N_PTS;
        int total4 = B * N_PTS / 4;
        transpose_kernel<<<dim3((total4 + 255) / 256), dim3(256), 0, stream>>>(
            pts, sx, sy, sz, total4);
        fused_knn_kernel<true><<<grid, TPB, 0, stream>>>(
            pts, sx, sy, sz, gmeans, covs, B);
    } else {
        fused_knn_kernel<false><<<grid, TPB, 0, stream>>>(
            pts, nullptr, nullptr, nullptr, gmeans, covs, B);
    }
    finalize_kernel<<<dim3(1), dim3(256), 0, stream>>>(gmeans, covs, out, B);
}